// Round 4
// baseline (152.361 us; speedup 1.0000x reference)
//
#include <hip/hip_runtime.h>

// out[o] with o = pair*25 + (m1*5+m2):  out = coef[m1*5+m2] * feat[pair*5 + (m1+m2-2)]
// coef[idx] = cg[m1*25+m2*5+m3] (0 when m3 out of range).
// Direct output-indexed streaming: each thread owns 4 consecutive output
// elements -> one coalesced float4 store. No data staging, no per-tile
// barriers. Coefficients live in a 25-entry LDS table (conflict-free).
// Feature reads are scalar but a wave's window is ~205 B -> L1-resident.
//
// R4 A/B: regular store instead of __builtin_nontemporal_store (R3: 89.2 us,
// 5.64 TB/s vs 6.85 TB/s pure-write fill — testing whether the nt flag is
// what keeps us off the write ceiling).

typedef float f32x4 __attribute__((ext_vector_type(4)));

__global__ __launch_bounds__(256) void tpe_direct(
    const float* __restrict__ feat, const float* __restrict__ cg,
    float* __restrict__ out, int nquads, int npairs) {
  __shared__ float coef[32];
  const int tid = threadIdx.x;
  if (tid < 25) {
    const int m1 = tid / 5, m2 = tid % 5, m3 = m1 + m2 - 2;
    coef[tid] = (m3 >= 0 && m3 < 5) ? cg[m1 * 25 + m2 * 5 + m3] : 0.0f;
  }
  __syncthreads();

  const int stride = gridDim.x * 256;
  for (int q = blockIdx.x * 256 + tid; q < nquads; q += stride) {
    const int o = q * 4;            // out_size = 104,857,600 < 2^31 -> int ok
    int pair = o / 25;              // compiler: magic mul_hi
    int idx = o - pair * 25;

    f32x4 v;
#pragma unroll
    for (int r = 0; r < 4; ++r) {
      // m1 = idx/5, m2 = idx%5, m3 = m1+m2-2; clamp m3 for the (coef==0) taps
      const int m1 = idx / 5;
      const int m2 = idx - m1 * 5;
      int m3 = m1 + m2 - 2;
      m3 = m3 < 0 ? 0 : (m3 > 4 ? 4 : m3);
      v[r] = coef[idx] * feat[pair * 5 + m3];
      // advance idx/pair for next element (4 < 25 -> at most one wrap)
      ++idx;
      if (idx == 25) { idx = 0; ++pair; }
    }
    *reinterpret_cast<f32x4*>(&out[o]) = v;
  }
}

extern "C" void kernel_launch(void* const* d_in, const int* in_sizes, int n_in,
                              void* d_out, int out_size, void* d_ws, size_t ws_size,
                              hipStream_t stream) {
  const float* feat = (const float*)d_in[0];
  const float* cg   = (const float*)d_in[1];
  float* out = (float*)d_out;

  const int npairs = in_sizes[0] / 5;       // B*N
  const int total = npairs * 25;            // == out_size, divisible by 4 here
  const int nquads = total / 4;
  int grid = (nquads + 255) / 256;
  if (grid > 2048) grid = 2048;

  tpe_direct<<<dim3(grid), dim3(256), 0, stream>>>(feat, cg, out, nquads, npairs);
}